// Round 2
// 322.449 us; speedup vs baseline: 1.0074x; 1.0074x over previous
//
#include <hip/hip_runtime.h>
#include <stdint.h>

#define A_ 128
#define S_ 512
#define D_ 768
#define C_ 16          // chunks per attention row-space (residues mod 16)
#define MASKID 103

typedef short bf16x8_t __attribute__((ext_vector_type(8)));
typedef float floatx4_t __attribute__((ext_vector_type(4)));

__device__ __forceinline__ unsigned short f2bf(float f) {
    union { unsigned int u; float f; } v; v.f = f;
    unsigned int u = v.u;
    return (unsigned short)((u + 0x7fffu + ((u >> 16) & 1u)) >> 16);
}

// ---------------------------------------------------------------------------
// Kernel 1: attention softmax partials (16 chunks/a for tail balance).
// blocks [0,2048): a = bx>>4, chunk c = bx&15; 4 waves; wave rows ≡ c+16w (mod 64)
// Lane d-layout: d = 4*lane + 256*j (j<3) -> each dwordx4 load is one
// contiguous 1 KB segment per wave.
// extra duties: c==0/wave0 writes mask-logit bf16 half of ws_x;
//               c==1/wave0 computes senti head (ONE wave = full 768-dot).
// blocks [2048,2112): gather 50 W_prob rows (fp32->bf16) AND convert
// W_dense fp32->bf16 (18432 floats per block).
// ---------------------------------------------------------------------------
__global__ __launch_bounds__(256) void attn_part(
    const float* __restrict__ bert,
    const int* __restrict__ ids,
    const int* __restrict__ length,
    const int* __restrict__ label_words,
    const float* __restrict__ W_prob,
    const float* __restrict__ b_prob,
    const float* __restrict__ W_dense,
    const float* __restrict__ W_senti,
    const float* __restrict__ b_senti,
    unsigned short* __restrict__ ws_Wpw,
    float* __restrict__ ws_bp,
    unsigned short* __restrict__ ws_Wd,
    unsigned short* __restrict__ ws_x,
    float* __restrict__ part_m,
    float* __restrict__ part_l,
    float* __restrict__ part_acc,
    float* __restrict__ d_out)
{
    int bx = blockIdx.x;
    int tid = threadIdx.x;
    if (bx >= A_ * C_) {               // ---- gather/convert branch (block-uniform)
        int r = bx - A_ * C_;          // [0, 64)
        if (r < 50) {
            int word = label_words[r];
            const float* src = W_prob + (size_t)word * D_;
            for (int j = tid; j < D_; j += 256) ws_Wpw[r * D_ + j] = f2bf(src[j]);
            if (tid == 0) ws_bp[r] = b_prob[word];
        } else {
            for (int j = tid; j < D_; j += 256) ws_Wpw[r * D_ + j] = 0;
            if (tid == 0) ws_bp[r] = 0.f;
        }
        // W_dense fp32 -> bf16: 768*1536 = 1179648 floats / 64 blocks = 18432
        const float4* src4 = (const float4*)(W_dense + (size_t)r * 18432);
        ushort4* dst4 = (ushort4*)(ws_Wd + (size_t)r * 18432);
#pragma unroll
        for (int it = 0; it < 18; it++) {
            float4 v = src4[tid + 256 * it];
            ushort4 o;
            o.x = f2bf(v.x); o.y = f2bf(v.y); o.z = f2bf(v.z); o.w = f2bf(v.w);
            dst4[tid + 256 * it] = o;
        }
        return;
    }
    int a = bx >> 4, c = bx & 15;
    int wave = tid >> 6, lane = tid & 63;
    int d0 = lane * 4;                 // + 256*j

    __shared__ int s_minpos;
    __shared__ float red_m[4], red_l[4];
    __shared__ float red_acc[4][D_];   // 12 KB

    const float* base = bert + (size_t)a * S_ * D_;

    // ---- senti head: chunk 1, wave 0 ONLY (one wave covers all 768 dims) ----
    if (c == 1 && wave == 0) {
        const float* q = base + d0;    // row 0
        float4 v0 = *(const float4*)(q);
        float4 v1 = *(const float4*)(q + 256);
        float4 v2 = *(const float4*)(q + 512);
        float4 u0 = *(const float4*)(W_senti + d0);
        float4 u1 = *(const float4*)(W_senti + d0 + 256);
        float4 u2 = *(const float4*)(W_senti + d0 + 512);
        float4 t0 = *(const float4*)(W_senti + D_ + d0);
        float4 t1 = *(const float4*)(W_senti + D_ + d0 + 256);
        float4 t2 = *(const float4*)(W_senti + D_ + d0 + 512);
        float rv[12], w0[12], w1[12];
        rv[0]=v0.x; rv[1]=v0.y; rv[2]=v0.z; rv[3]=v0.w;
        rv[4]=v1.x; rv[5]=v1.y; rv[6]=v1.z; rv[7]=v1.w;
        rv[8]=v2.x; rv[9]=v2.y; rv[10]=v2.z; rv[11]=v2.w;
        w0[0]=u0.x; w0[1]=u0.y; w0[2]=u0.z; w0[3]=u0.w;
        w0[4]=u1.x; w0[5]=u1.y; w0[6]=u1.z; w0[7]=u1.w;
        w0[8]=u2.x; w0[9]=u2.y; w0[10]=u2.z; w0[11]=u2.w;
        w1[0]=t0.x; w1[1]=t0.y; w1[2]=t0.z; w1[3]=t0.w;
        w1[4]=t1.x; w1[5]=t1.y; w1[6]=t1.z; w1[7]=t1.w;
        w1[8]=t2.x; w1[9]=t2.y; w1[10]=t2.z; w1[11]=t2.w;
        float p0 = 0.f, p1 = 0.f;
#pragma unroll
        for (int k = 0; k < 12; k++) { p0 = fmaf(rv[k], w0[k], p0); p1 = fmaf(rv[k], w1[k], p1); }
#pragma unroll
        for (int off = 32; off >= 1; off >>= 1) {
            p0 += __shfl_xor(p0, off, 64);
            p1 += __shfl_xor(p1, off, 64);
        }
        if (lane == 0) {
            d_out[a * 2 + 0] = p0 + b_senti[0];
            d_out[a * 2 + 1] = p1 + b_senti[1];
        }
    }

    if (tid == 0) s_minpos = S_;
    __syncthreads();
    for (int p = tid; p < S_; p += 256)
        if (ids[a * S_ + p] == MASKID) atomicMin(&s_minpos, p);
    __syncthreads();
    int mp = (s_minpos >= S_) ? 0 : s_minpos;

    // mask_logit slice for this lane (12 floats, coalesced layout)
    float ml[12];
    {
        const float* q = base + (size_t)mp * D_ + d0;
        float4 v0 = *(const float4*)(q);
        float4 v1 = *(const float4*)(q + 256);
        float4 v2 = *(const float4*)(q + 512);
        ml[0]=v0.x; ml[1]=v0.y; ml[2]=v0.z; ml[3]=v0.w;
        ml[4]=v1.x; ml[5]=v1.y; ml[6]=v1.z; ml[7]=v1.w;
        ml[8]=v2.x; ml[9]=v2.y; ml[10]=v2.z; ml[11]=v2.w;
    }
    // chunk 0 / wave 0 writes the mask-logit bf16 half of ws_x directly
    if (c == 0 && wave == 0) {
#pragma unroll
        for (int j = 0; j < 3; j++) {
            ushort4 o;
            o.x = f2bf(ml[4*j]);   o.y = f2bf(ml[4*j+1]);
            o.z = f2bf(ml[4*j+2]); o.w = f2bf(ml[4*j+3]);
            *(ushort4*)(ws_x + (size_t)a * 1536 + D_ + d0 + 256 * j) = o;
        }
    }
    int len = length[a]; if (len > S_ - 3) len = S_ - 3;

    float m = -3.0e38f, l = 0.f;
    float acc[12];
#pragma unroll
    for (int k = 0; k < 12; k++) acc[k] = 0.f;

    int v = c + 16 * wave;             // wave handles rows ≡ c+16w (mod 64)
    // -------- paired iterations: rows v and v+64 --------
    for (; v + 64 < len; v += 128) {
        const float* qa = base + (size_t)(3 + v) * D_ + d0;
        const float* qb = base + (size_t)(3 + v + 64) * D_ + d0;
        float4 a0 = *(const float4*)(qa);
        float4 a1 = *(const float4*)(qa + 256);
        float4 a2 = *(const float4*)(qa + 512);
        float4 b0 = *(const float4*)(qb);
        float4 b1 = *(const float4*)(qb + 256);
        float4 b2 = *(const float4*)(qb + 512);
        float ra[12], rb[12];
        ra[0]=a0.x; ra[1]=a0.y; ra[2]=a0.z; ra[3]=a0.w;
        ra[4]=a1.x; ra[5]=a1.y; ra[6]=a1.z; ra[7]=a1.w;
        ra[8]=a2.x; ra[9]=a2.y; ra[10]=a2.z; ra[11]=a2.w;
        rb[0]=b0.x; rb[1]=b0.y; rb[2]=b0.z; rb[3]=b0.w;
        rb[4]=b1.x; rb[5]=b1.y; rb[6]=b1.z; rb[7]=b1.w;
        rb[8]=b2.x; rb[9]=b2.y; rb[10]=b2.z; rb[11]=b2.w;
        float pa = 0.f, pb = 0.f;
#pragma unroll
        for (int k = 0; k < 12; k++) { pa = fmaf(ra[k], ml[k], pa); pb = fmaf(rb[k], ml[k], pb); }
#pragma unroll
        for (int off = 32; off >= 1; off >>= 1) {
            pa += __shfl_xor(pa, off, 64);
            pb += __shfl_xor(pb, off, 64);
        }
        float mn = fmaxf(m, fmaxf(pa, pb));
        float alpha = __expf(m - mn);
        float wa = __expf(pa - mn);
        float wb = __expf(pb - mn);
        l = l * alpha + wa + wb;
#pragma unroll
        for (int k = 0; k < 12; k++)
            acc[k] = fmaf(acc[k], alpha, fmaf(wa, ra[k], wb * rb[k]));
        m = mn;
    }
    // -------- single tail --------
    for (; v < len; v += 64) {
        const float* qa = base + (size_t)(3 + v) * D_ + d0;
        float4 a0 = *(const float4*)(qa);
        float4 a1 = *(const float4*)(qa + 256);
        float4 a2 = *(const float4*)(qa + 512);
        float ra[12];
        ra[0]=a0.x; ra[1]=a0.y; ra[2]=a0.z; ra[3]=a0.w;
        ra[4]=a1.x; ra[5]=a1.y; ra[6]=a1.z; ra[7]=a1.w;
        ra[8]=a2.x; ra[9]=a2.y; ra[10]=a2.z; ra[11]=a2.w;
        float pa = 0.f;
#pragma unroll
        for (int k = 0; k < 12; k++) pa = fmaf(ra[k], ml[k], pa);
#pragma unroll
        for (int off = 32; off >= 1; off >>= 1)
            pa += __shfl_xor(pa, off, 64);
        float mn = fmaxf(m, pa);
        float alpha = __expf(m - mn);
        float wa = __expf(pa - mn);
        l = l * alpha + wa;
#pragma unroll
        for (int k = 0; k < 12; k++) acc[k] = fmaf(acc[k], alpha, wa * ra[k]);
        m = mn;
    }
    if (lane == 0) { red_m[wave] = m; red_l[wave] = l; }
#pragma unroll
    for (int j = 0; j < 3; j++) {
        floatx4_t t = { acc[4*j], acc[4*j+1], acc[4*j+2], acc[4*j+3] };
        *(floatx4_t*)&red_acc[wave][d0 + 256 * j] = t;
    }
    __syncthreads();

    float m0 = red_m[0], m1 = red_m[1], m2 = red_m[2], m3 = red_m[3];
    float M = fmaxf(fmaxf(m0, m1), fmaxf(m2, m3));
    float f0 = __expf(m0 - M), f1 = __expf(m1 - M);
    float f2 = __expf(m2 - M), f3 = __expf(m3 - M);
    int pc = (a * C_ + c) * D_;
#pragma unroll
    for (int e = 0; e < 3; e++) {
        int d = tid + 256 * e;
        part_acc[pc + d] = f0 * red_acc[0][d] + f1 * red_acc[1][d]
                         + f2 * red_acc[2][d] + f3 * red_acc[3][d];
    }
    if (tid == 0) {
        part_m[a * C_ + c] = M;
        part_l[a * C_ + c] = f0 * red_l[0] + f1 * red_l[1] + f2 * red_l[2] + f3 * red_l[3];
    }
}

// ---------------------------------------------------------------------------
// Kernel 2: merge 16 chunk partials -> att (bf16 into ws_x first half).
// No bert access anymore (mask half + senti moved into kernel 1).
// ---------------------------------------------------------------------------
__global__ __launch_bounds__(256) void merge_kernel(
    const float* __restrict__ part_m,
    const float* __restrict__ part_l,
    const float* __restrict__ part_acc,
    unsigned short* __restrict__ ws_x)
{
    int a = blockIdx.x, tid = threadIdx.x;
    float mc[C_], lc[C_];
#pragma unroll
    for (int c = 0; c < C_; c++) { mc[c] = part_m[a * C_ + c]; lc[c] = part_l[a * C_ + c]; }
    float M = mc[0];
#pragma unroll
    for (int c = 1; c < C_; c++) M = fmaxf(M, mc[c]);
    float fac[C_]; float denom = 0.f;
#pragma unroll
    for (int c = 0; c < C_; c++) { fac[c] = __expf(mc[c] - M); denom += fac[c] * lc[c]; }
    float inv = 1.0f / fmaxf(denom, 1e-30f);

    const float* pa = part_acc + (size_t)a * C_ * D_;
#pragma unroll
    for (int e = 0; e < 3; e++) {
        int d = tid + 256 * e;
        float s = 0.f;
#pragma unroll
        for (int c = 0; c < C_; c++) s = fmaf(fac[c], pa[c * D_ + d], s);
        ws_x[(size_t)a * 1536 + d] = f2bf(s * inv);
    }
}

// ---------------------------------------------------------------------------
// Kernel 3: h = tanh(x @ W_dense.T + b_dense), MFMA bf16, M=128 N=768 K=1536.
// One 16x16 tile per block (384 blocks), 4-wave K-split, bf16 B from ws_Wd.
// ---------------------------------------------------------------------------
__global__ __launch_bounds__(256) void dense_kernel(
    const unsigned short* __restrict__ ws_x,
    const unsigned short* __restrict__ ws_Wd,
    const float* __restrict__ b_dense,
    unsigned short* __restrict__ ws_h)
{
    int tid = threadIdx.x;
    int wave = tid >> 6, lane = tid & 63;
    int r = lane & 15, q = lane >> 4;
    int T = blockIdx.x;                // [0, 384)
    int m_t = T / 48, n_t = T % 48;
    const bf16x8_t* Ap = (const bf16x8_t*)(ws_x  + (size_t)(m_t * 16 + r) * 1536 + wave * 384 + q * 8);
    const bf16x8_t* Bp = (const bf16x8_t*)(ws_Wd + (size_t)(n_t * 16 + r) * 1536 + wave * 384 + q * 8);
    floatx4_t acc = {0.f, 0.f, 0.f, 0.f};
#pragma unroll
    for (int kk = 0; kk < 12; kk++)
        acc = __builtin_amdgcn_mfma_f32_16x16x32_bf16(Ap[kk * 4], Bp[kk * 4], acc, 0, 0, 0);
    __shared__ float part[4][256];
#pragma unroll
    for (int reg = 0; reg < 4; reg++)
        part[wave][(q * 4 + reg) * 16 + r] = acc[reg];   // row*16+col
    __syncthreads();
    float sum = part[0][tid] + part[1][tid] + part[2][tid] + part[3][tid];
    int row = tid >> 4, col = tid & 15;
    int n = n_t * 16 + col;
    float h = tanhf(sum + b_dense[n]);
    ws_h[(size_t)(m_t * 16 + row) * D_ + n] = f2bf(h);
}

// ---------------------------------------------------------------------------
// Kernel 4: lp = tanh(h @ Wpw.T + bp) (M=128 N=64 K=768) + final einsum
// ---------------------------------------------------------------------------
__global__ __launch_bounds__(256) void label_kernel(
    const unsigned short* __restrict__ ws_h,
    const unsigned short* __restrict__ ws_Wpw,
    const float* __restrict__ ws_bp,
    const float* __restrict__ W_lab,
    float* __restrict__ d_out)
{
    int tid = threadIdx.x;
    int wave = tid >> 6, lane = tid & 63;
    int r = lane & 15, q = lane >> 4;
    int m_t = blockIdx.x;       // 8 blocks
    int n_t = wave;             // 4 n-tiles
    const bf16x8_t* Ap = (const bf16x8_t*)(ws_h + (size_t)(m_t * 16 + r) * 768 + q * 8);
    const bf16x8_t* Bp = (const bf16x8_t*)(ws_Wpw + (size_t)(n_t * 16 + r) * 768 + q * 8);
    floatx4_t acc = {0.f, 0.f, 0.f, 0.f};
#pragma unroll
    for (int kk = 0; kk < 24; kk++)
        acc = __builtin_amdgcn_mfma_f32_16x16x32_bf16(Ap[kk * 4], Bp[kk * 4], acc, 0, 0, 0);
    __shared__ float lp_s[16][64];
    int col = n_t * 16 + r;
    float bp = ws_bp[col];
#pragma unroll
    for (int reg = 0; reg < 4; reg++)
        lp_s[q * 4 + reg][col] = tanhf(acc[reg] + bp);
    __syncthreads();
    for (int t = tid; t < 320; t += 256) {
        int al = t / 20, rem = t % 20;
        int k = rem / 10, lb = rem % 10;
        float s = 0.f;
#pragma unroll
        for (int w = 0; w < 5; w++)
            s = fmaf(lp_s[al][lb * 5 + w], W_lab[(lb * 2 + k) * 5 + w], s);
        d_out[256 + (m_t * 16 + al) * 20 + rem] = s;
    }
}

extern "C" void kernel_launch(void* const* d_in, const int* in_sizes, int n_in,
                              void* d_out, int out_size, void* d_ws, size_t ws_size,
                              hipStream_t stream) {
    const float* bert    = (const float*)d_in[0];
    const int* ids       = (const int*)d_in[1];
    const int* length    = (const int*)d_in[2];
    const int* label_words = (const int*)d_in[3];
    const float* W_senti = (const float*)d_in[4];
    const float* b_senti = (const float*)d_in[5];
    const float* W_dense = (const float*)d_in[6];
    const float* b_dense = (const float*)d_in[7];
    const float* W_prob  = (const float*)d_in[8];
    const float* b_prob  = (const float*)d_in[9];
    const float* W_lab   = (const float*)d_in[10];
    float* out = (float*)d_out;

    char* ws = (char*)d_ws;
    unsigned short* ws_x   = (unsigned short*)(ws + 0);         // 393216 B
    unsigned short* ws_h   = (unsigned short*)(ws + 393216);    // 196608 B
    unsigned short* ws_Wpw = (unsigned short*)(ws + 589824);    //  98304 B
    float*          ws_bp  = (float*)(ws + 688128);             //    256 B
    unsigned short* ws_Wd  = (unsigned short*)(ws + 688384);    // 2359296 B
    float*          part_m = (float*)(ws + 3047680);            //   8192 B
    float*          part_l = (float*)(ws + 3055872);            //   8192 B
    float*        part_acc = (float*)(ws + 3064064);            // 6291456 B

    attn_part<<<A_ * C_ + 64, 256, 0, stream>>>(bert, ids, length, label_words,
        W_prob, b_prob, W_dense, W_senti, b_senti,
        ws_Wpw, ws_bp, ws_Wd, ws_x, part_m, part_l, part_acc, out);
    merge_kernel<<<A_, 256, 0, stream>>>(part_m, part_l, part_acc, ws_x);
    dense_kernel<<<384, 256, 0, stream>>>(ws_x, ws_Wd, b_dense, ws_h);
    label_kernel<<<8, 256, 0, stream>>>(ws_h, ws_Wpw, ws_bp, W_lab, out);
}